// Round 1
// baseline (613.442 us; speedup 1.0000x reference)
//
#include <hip/hip_runtime.h>
#include <hip/hip_bf16.h>

#define S_IMG 16384
#define N_TXT 4096
#define DIM   512
#define KDIM  512

typedef __attribute__((ext_vector_type(8))) short bf16x8;
typedef __attribute__((ext_vector_type(4))) float f32x4;

__device__ __forceinline__ short f2bf(float f) {
  unsigned u = __float_as_uint(f);
  u += 0x7FFFu + ((u >> 16) & 1u);   // RNE
  return (short)(u >> 16);
}

__device__ __forceinline__ float softplus_f(float x) {
  // numerically-stable softplus, matches logaddexp(x, 0) shape
  return fmaxf(x, 0.0f) + log1pf(expf(-fabsf(x)));
}

// ---------------- init: sentinel for segment-min, zero the loss accumulator ----
__global__ void init_kernel(unsigned long long* __restrict__ packed,
                            float* __restrict__ out_loss) {
  const int i = blockIdx.x * 256 + threadIdx.x;
  packed[i] = 0xFFFFFFFFFFFFFFFFull;
  if (i == 0) out_loss[0] = 0.0f;
}

// ---------------- L2 normalize rows, emit f32 (output) + bf16 (for MFMA) ------
__global__ void normalize_kernel(const float* __restrict__ in,
                                 float* __restrict__ outf,
                                 short* __restrict__ outb) {
  const int w = threadIdx.x >> 6, l = threadIdx.x & 63;
  const size_t row = (size_t)blockIdx.x * 4 + w;
  const float4* r4 = (const float4*)(in + row * DIM);
  float4 a = r4[l], b = r4[l + 64];
  float s = a.x*a.x + a.y*a.y + a.z*a.z + a.w*a.w
          + b.x*b.x + b.y*b.y + b.z*b.z + b.w*b.w;
#pragma unroll
  for (int off = 32; off; off >>= 1) s += __shfl_xor(s, off, 64);
  const float inv = 1.0f / (sqrtf(s) + 1e-12f);
  a.x *= inv; a.y *= inv; a.z *= inv; a.w *= inv;
  b.x *= inv; b.y *= inv; b.z *= inv; b.w *= inv;
  float4* o4 = (float4*)(outf + row * DIM);
  o4[l] = a; o4[l + 64] = b;
  int2 pa, pb;
  pa.x = (f2bf(a.x) & 0xFFFF) | ((int)f2bf(a.y) << 16);
  pa.y = (f2bf(a.z) & 0xFFFF) | ((int)f2bf(a.w) << 16);
  pb.x = (f2bf(b.x) & 0xFFFF) | ((int)f2bf(b.y) << 16);
  pb.y = (f2bf(b.z) & 0xFFFF) | ((int)f2bf(b.w) << 16);
  ((int2*)(outb + row * DIM))[l]       = pa;
  ((int2*)(outb + row * DIM + 256))[l] = pb;
}

// ---------------- exact-f32 true-positive logits + packed segment-min ---------
__global__ void tp_select_kernel(const float* __restrict__ zimg,
                                 const float* __restrict__ ztxt,
                                 const int* __restrict__ key,
                                 unsigned long long* __restrict__ packed,
                                 const float* __restrict__ logt_p,
                                 const float* __restrict__ bias_p) {
  const int w = threadIdx.x >> 6, l = threadIdx.x & 63;
  const int i = blockIdx.x * 4 + w;
  const int k = key[i];
  const float4* zi = (const float4*)(zimg + (size_t)i * DIM);
  const float4* zt = (const float4*)(ztxt + (size_t)k * DIM);
  float4 a0 = zi[l], a1 = zi[l + 64], b0 = zt[l], b1 = zt[l + 64];
  float s = a0.x*b0.x + a0.y*b0.y + a0.z*b0.z + a0.w*b0.w
          + a1.x*b1.x + a1.y*b1.y + a1.z*b1.z + a1.w*b1.w;
#pragma unroll
  for (int off = 32; off; off >>= 1) s += __shfl_xor(s, off, 64);
  if (l == 0) {
    const float t  = expf(logt_p[0]);
    const float tp = s * t + bias_p[0];
    const float loss = softplus_f(-tp);          // > 0 always -> bit order ok
    const unsigned long long p =
        ((unsigned long long)__float_as_uint(loss) << 32) | (unsigned)i;
    atomicMin(&packed[k], p);                    // lexicographic (loss, index)
  }
}

// ---------------- select winners, gather bf16 rows (zero if no image) --------
__global__ void gather_kernel(const unsigned long long* __restrict__ packed,
                              float* __restrict__ out_idx,
                              const short* __restrict__ zimgb,
                              short* __restrict__ zselb) {
  const int w = threadIdx.x >> 6, l = threadIdx.x & 63;
  const int n = blockIdx.x * 4 + w;
  const unsigned long long p = packed[n];
  int4 v = {0, 0, 0, 0};
  float f = -1.0f;
  if (p != 0xFFFFFFFFFFFFFFFFull) {
    const int sel = (int)(p & 0xFFFFFFFFull);
    f = (float)sel;
    v = ((const int4*)(zimgb + (size_t)sel * DIM))[l];
  }
  ((int4*)(zselb + (size_t)n * DIM))[l] = v;
  if (l == 0) out_idx[n] = f;
}

// ---------------- bf16 MFMA GEMM: C = A * B^T * t + bias (opt. fused loss) ----
// 128x128 tile, BK=32, 4 waves 2x2, 4x4 mfma_f32_16x16x32_bf16 per wave.
// global_load_lds width=16 staging; XOR swizzle on 16B k-chunks applied on the
// GLOBAL read side so ds_read_b128 is 2-way bank-aliased (free).
template <bool FUSE_LOSS>
__global__ void gemm_bt(const short* __restrict__ A, const short* __restrict__ B,
                        float* __restrict__ C, const int Ncols,
                        const float* __restrict__ logt_p,
                        const float* __restrict__ bias_p,
                        float* __restrict__ loss_out) {
  __shared__ alignas(16) short As[128 * 32];
  __shared__ alignas(16) short Bs[128 * 32];
  __shared__ float red[4];

  const int t = threadIdx.x;
  const int w = t >> 6, l = t & 63;
  const int wm = w >> 1, wn = w & 1;
  const int bm = blockIdx.x * 128, bn = blockIdx.y * 128;
  const int fr = l & 15, quad = l >> 4;

  const int srow_base = (w << 4) + (l >> 2);   // staging row within 64-row group
  const int sq = l & 3;                        // staging 16B chunk

  f32x4 acc[4][4] = {};

  for (int k0 = 0; k0 < KDIM; k0 += 32) {
    __syncthreads();  // prior iter's ds_reads done before LDS overwrite
#pragma unroll
    for (int c = 0; c < 2; ++c) {
      const int row = c * 64 + srow_base;
      const int qg = sq ^ ((row >> 1) & 3);
      const short* gpa = A + (size_t)(bm + row) * KDIM + k0 + qg * 8;
      const short* lpa = &As[(c * 64 + (w << 4)) * 32];  // wave-uniform base
      __builtin_amdgcn_global_load_lds(
          (const __attribute__((address_space(1))) void*)gpa,
          (__attribute__((address_space(3))) void*)lpa, 16, 0, 0);
      const short* gpb = B + (size_t)(bn + row) * KDIM + k0 + qg * 8;
      const short* lpb = &Bs[(c * 64 + (w << 4)) * 32];
      __builtin_amdgcn_global_load_lds(
          (const __attribute__((address_space(1))) void*)gpb,
          (__attribute__((address_space(3))) void*)lpb, 16, 0, 0);
    }
    __syncthreads();  // drains vmcnt(0): staged data visible

    bf16x8 af[4], bf[4];
#pragma unroll
    for (int mi = 0; mi < 4; ++mi) {
      const int ar = wm * 64 + mi * 16 + fr;
      af[mi] = *(const bf16x8*)&As[ar * 32 + (quad ^ ((ar >> 1) & 3)) * 8];
      const int br = wn * 64 + mi * 16 + fr;
      bf[mi] = *(const bf16x8*)&Bs[br * 32 + (quad ^ ((br >> 1) & 3)) * 8];
    }
#pragma unroll
    for (int mi = 0; mi < 4; ++mi)
#pragma unroll
      for (int nj = 0; nj < 4; ++nj)
        acc[mi][nj] = __builtin_amdgcn_mfma_f32_16x16x32_bf16(
            af[mi], bf[nj], acc[mi][nj], 0, 0, 0);
  }

  const float tt = expf(logt_p[0]);
  const float bb = bias_p[0];
  float lsum = 0.0f;
#pragma unroll
  for (int mi = 0; mi < 4; ++mi) {
#pragma unroll
    for (int nj = 0; nj < 4; ++nj) {
      const int grow0 = bm + wm * 64 + mi * 16 + quad * 4;
      const int gcol  = bn + wn * 64 + nj * 16 + fr;
      f32x4 a = acc[mi][nj];
#pragma unroll
      for (int r = 0; r < 4; ++r) {
        const float v = a[r] * tt + bb;
        C[(size_t)(grow0 + r) * Ncols + gcol] = v;
        if (FUSE_LOSS) {
          const float lab = (grow0 + r == gcol) ? 1.0f : -1.0f;
          lsum += softplus_f(-lab * v);
        }
      }
    }
  }
  if (FUSE_LOSS) {
#pragma unroll
    for (int off = 32; off; off >>= 1) lsum += __shfl_xor(lsum, off, 64);
    if (l == 0) red[w] = lsum;
    __syncthreads();
    if (t == 0)
      atomicAdd(loss_out, (red[0] + red[1] + red[2] + red[3]) * (1.0f / N_TXT));
  }
}

// ---------------- launch --------------------------------------------------------
extern "C" void kernel_launch(void* const* d_in, const int* in_sizes, int n_in,
                              void* d_out, int out_size, void* d_ws, size_t ws_size,
                              hipStream_t stream) {
  const float* img  = (const float*)d_in[0];
  const float* txt  = (const float*)d_in[1];
  const int*   key  = (const int*)d_in[2];
  const float* logt = (const float*)d_in[3];
  const float* bias = (const float*)d_in[4];

  float* out    = (float*)d_out;
  float* o_loss = out;                                   // [1]
  float* o_sel  = out + 1;                               // [N]
  float* o_zimg = o_sel + N_TXT;                         // [S, 512]
  float* o_ztxt = o_zimg + (size_t)S_IMG * DIM;          // [N, 512]
  float* o_ap   = o_ztxt + (size_t)N_TXT * DIM;          // [S, N]
  float* o_fl   = o_ap + (size_t)S_IMG * N_TXT;          // [N, N]

  char* ws = (char*)d_ws;
  short* zimgb = (short*)ws;                                         // 16 MB
  short* ztxtb = (short*)(ws + (size_t)S_IMG * DIM * 2);             //  4 MB
  short* zselb = (short*)(ws + (size_t)(S_IMG + N_TXT) * DIM * 2);   //  4 MB
  unsigned long long* packed =
      (unsigned long long*)(ws + (size_t)(S_IMG + 2 * N_TXT) * DIM * 2);

  init_kernel<<<N_TXT / 256, 256, 0, stream>>>(packed, o_loss);
  normalize_kernel<<<S_IMG / 4, 256, 0, stream>>>(img, o_zimg, zimgb);
  normalize_kernel<<<N_TXT / 4, 256, 0, stream>>>(txt, o_ztxt, ztxtb);
  tp_select_kernel<<<S_IMG / 4, 256, 0, stream>>>(o_zimg, o_ztxt, key, packed,
                                                  logt, bias);
  gather_kernel<<<N_TXT / 4, 256, 0, stream>>>(packed, o_sel, zimgb, zselb);
  gemm_bt<false><<<dim3(S_IMG / 128, N_TXT / 128), 256, 0, stream>>>(
      zimgb, ztxtb, o_ap, N_TXT, logt, bias, nullptr);
  gemm_bt<true><<<dim3(N_TXT / 128, N_TXT / 128), 256, 0, stream>>>(
      zselb, ztxtb, o_fl, N_TXT, logt, bias, o_loss);
}

// Round 2
// 574.390 us; speedup vs baseline: 1.0680x; 1.0680x over previous
//
#include <hip/hip_runtime.h>
#include <hip/hip_bf16.h>

#define S_IMG 16384
#define N_TXT 4096
#define DIM   512
#define KDIM  512

typedef __attribute__((ext_vector_type(8))) short bf16x8;
typedef __attribute__((ext_vector_type(4))) float f32x4;

__device__ __forceinline__ short f2bf(float f) {
  unsigned u = __float_as_uint(f);
  u += 0x7FFFu + ((u >> 16) & 1u);   // RNE
  return (short)(u >> 16);
}

__device__ __forceinline__ float softplus_f(float x) {
  return fmaxf(x, 0.0f) + log1pf(expf(-fabsf(x)));
}

// ---------------- init: sentinel for segment-min, zero the loss accumulator ----
__global__ __launch_bounds__(256) void init_kernel(
    unsigned long long* __restrict__ packed, float* __restrict__ out_loss) {
  const int i = blockIdx.x * 256 + threadIdx.x;
  packed[i] = 0xFFFFFFFFFFFFFFFFull;
  if (i == 0) out_loss[0] = 0.0f;
}

// ---------------- L2 normalize rows, emit f32 (output) + bf16 (for MFMA) ------
__global__ __launch_bounds__(256) void normalize_kernel(
    const float* __restrict__ in, float* __restrict__ outf,
    short* __restrict__ outb) {
  const int w = threadIdx.x >> 6, l = threadIdx.x & 63;
  const size_t row = (size_t)blockIdx.x * 4 + w;
  const float4* r4 = (const float4*)(in + row * DIM);
  float4 a = r4[l], b = r4[l + 64];
  float s = a.x*a.x + a.y*a.y + a.z*a.z + a.w*a.w
          + b.x*b.x + b.y*b.y + b.z*b.z + b.w*b.w;
#pragma unroll
  for (int off = 32; off; off >>= 1) s += __shfl_xor(s, off, 64);
  const float inv = 1.0f / (sqrtf(s) + 1e-12f);
  a.x *= inv; a.y *= inv; a.z *= inv; a.w *= inv;
  b.x *= inv; b.y *= inv; b.z *= inv; b.w *= inv;
  float4* o4 = (float4*)(outf + row * DIM);
  o4[l] = a; o4[l + 64] = b;
  int2 pa, pb;
  pa.x = (f2bf(a.x) & 0xFFFF) | ((int)f2bf(a.y) << 16);
  pa.y = (f2bf(a.z) & 0xFFFF) | ((int)f2bf(a.w) << 16);
  pb.x = (f2bf(b.x) & 0xFFFF) | ((int)f2bf(b.y) << 16);
  pb.y = (f2bf(b.z) & 0xFFFF) | ((int)f2bf(b.w) << 16);
  ((int2*)(outb + row * DIM))[l]       = pa;
  ((int2*)(outb + row * DIM + 256))[l] = pb;
}

// ---------------- exact-f32 true-positive logits + packed segment-min ---------
__global__ __launch_bounds__(256) void tp_select_kernel(
    const float* __restrict__ zimg, const float* __restrict__ ztxt,
    const int* __restrict__ key, unsigned long long* __restrict__ packed,
    const float* __restrict__ logt_p, const float* __restrict__ bias_p) {
  const int w = threadIdx.x >> 6, l = threadIdx.x & 63;
  const int i = blockIdx.x * 4 + w;
  const int k = key[i];
  const float4* zi = (const float4*)(zimg + (size_t)i * DIM);
  const float4* zt = (const float4*)(ztxt + (size_t)k * DIM);
  float4 a0 = zi[l], a1 = zi[l + 64], b0 = zt[l], b1 = zt[l + 64];
  float s = a0.x*b0.x + a0.y*b0.y + a0.z*b0.z + a0.w*b0.w
          + a1.x*b1.x + a1.y*b1.y + a1.z*b1.z + a1.w*b1.w;
#pragma unroll
  for (int off = 32; off; off >>= 1) s += __shfl_xor(s, off, 64);
  if (l == 0) {
    const float t  = expf(logt_p[0]);
    const float tp = s * t + bias_p[0];
    const float loss = softplus_f(-tp);          // > 0 -> float bit order = value order
    const unsigned long long p =
        ((unsigned long long)__float_as_uint(loss) << 32) | (unsigned)i;
    atomicMin(&packed[k], p);                    // lexicographic (loss, index)
  }
}

// ---------------- select winners, gather bf16 rows (zero if no image) --------
__global__ __launch_bounds__(256) void gather_kernel(
    const unsigned long long* __restrict__ packed, float* __restrict__ out_idx,
    const short* __restrict__ zimgb, short* __restrict__ zselb) {
  const int w = threadIdx.x >> 6, l = threadIdx.x & 63;
  const int n = blockIdx.x * 4 + w;
  const unsigned long long p = packed[n];
  int4 v = {0, 0, 0, 0};
  float f = -1.0f;
  if (p != 0xFFFFFFFFFFFFFFFFull) {
    const int sel = (int)(p & 0xFFFFFFFFull);
    f = (float)sel;
    v = ((const int4*)(zimgb + (size_t)sel * DIM))[l];
  }
  ((int4*)(zselb + (size_t)n * DIM))[l] = v;
  if (l == 0) out_idx[n] = f;
}

// ---------------- merged bf16 MFMA GEMM ---------------------------------------
// blockIdx.y < 128 : C_ap[bm..][bn..] = zimg * ztxt^T * t + b          (no loss)
// blockIdx.y >= 128: C_fl[...]        = zsel * ztxt^T * t + b, fused loss
// 128x128 tile, BK=32, 4 waves 2x2, 4x4 mfma_f32_16x16x32_bf16 per wave.
// global_load_lds width=16; XOR swizzle of 16B k-chunks applied on the GLOBAL
// read side (LDS dest of global_load_lds must be lane-contiguous).
// __launch_bounds__(256): REQUIRED — without it the backend assumes 1024-thread
// blocks and caps VGPRs at 128 -> the 64-reg accumulator spills to scratch.
__global__ __launch_bounds__(256) void gemm_merged(
    const short* __restrict__ Aimg, const short* __restrict__ Asel,
    const short* __restrict__ B, float* __restrict__ Cap,
    float* __restrict__ Cfl, const float* __restrict__ logt_p,
    const float* __restrict__ bias_p, float* __restrict__ loss_out) {
  __shared__ alignas(16) short As[128 * 32];
  __shared__ alignas(16) short Bs[128 * 32];
  __shared__ float red[4];

  const int t = threadIdx.x;
  const int w = t >> 6, l = t & 63;
  const int wm = w >> 1, wn = w & 1;
  const int bn = blockIdx.x * 128;               // x = col-block (fastest: B reuse)
  const bool fuse = (blockIdx.y >= 128);
  const int bm = (fuse ? (blockIdx.y - 128) : blockIdx.y) * 128;
  const short* A = fuse ? Asel : Aimg;
  float* C = fuse ? Cfl : Cap;
  const int fr = l & 15, quad = l >> 4;

  const int srow_base = (w << 4) + (l >> 2);     // staging row within 64-row group
  const int sq = l & 3;                          // staging 16B chunk

  f32x4 acc[4][4] = {};

  for (int k0 = 0; k0 < KDIM; k0 += 32) {
    __syncthreads();  // prior iter's ds_reads done before LDS overwrite
#pragma unroll
    for (int c = 0; c < 2; ++c) {
      const int row = c * 64 + srow_base;
      const int qg = sq ^ ((row >> 1) & 3);
      const short* gpa = A + (size_t)(bm + row) * KDIM + k0 + qg * 8;
      const short* lpa = &As[(c * 64 + (w << 4)) * 32];  // wave-uniform base
      __builtin_amdgcn_global_load_lds(
          (const __attribute__((address_space(1))) void*)gpa,
          (__attribute__((address_space(3))) void*)lpa, 16, 0, 0);
      const short* gpb = B + (size_t)(bn + row) * KDIM + k0 + qg * 8;
      const short* lpb = &Bs[(c * 64 + (w << 4)) * 32];
      __builtin_amdgcn_global_load_lds(
          (const __attribute__((address_space(1))) void*)gpb,
          (__attribute__((address_space(3))) void*)lpb, 16, 0, 0);
    }
    __syncthreads();  // drains vmcnt(0): staged data visible

    bf16x8 af[4], bfr[4];
#pragma unroll
    for (int mi = 0; mi < 4; ++mi) {
      const int ar = wm * 64 + mi * 16 + fr;
      af[mi] = *(const bf16x8*)&As[ar * 32 + (quad ^ ((ar >> 1) & 3)) * 8];
      const int br = wn * 64 + mi * 16 + fr;
      bfr[mi] = *(const bf16x8*)&Bs[br * 32 + (quad ^ ((br >> 1) & 3)) * 8];
    }
#pragma unroll
    for (int mi = 0; mi < 4; ++mi)
#pragma unroll
      for (int nj = 0; nj < 4; ++nj)
        acc[mi][nj] = __builtin_amdgcn_mfma_f32_16x16x32_bf16(
            af[mi], bfr[nj], acc[mi][nj], 0, 0, 0);
  }

  const float tt = expf(logt_p[0]);
  const float bb = bias_p[0];
  float lsum = 0.0f;
#pragma unroll
  for (int mi = 0; mi < 4; ++mi) {
#pragma unroll
    for (int nj = 0; nj < 4; ++nj) {
      const int grow0 = bm + wm * 64 + mi * 16 + quad * 4;
      const int gcol  = bn + wn * 64 + nj * 16 + fr;
      f32x4 a = acc[mi][nj];
#pragma unroll
      for (int r = 0; r < 4; ++r) {
        const float v = a[r] * tt + bb;
        C[(size_t)(grow0 + r) * N_TXT + gcol] = v;
        if (fuse) {
          const float lab = (grow0 + r == gcol) ? 1.0f : -1.0f;
          lsum += softplus_f(-lab * v);
        }
      }
    }
  }
  if (fuse) {
#pragma unroll
    for (int off = 32; off; off >>= 1) lsum += __shfl_xor(lsum, off, 64);
    if (l == 0) red[w] = lsum;
    __syncthreads();
    if (t == 0)
      atomicAdd(loss_out, (red[0] + red[1] + red[2] + red[3]) * (1.0f / N_TXT));
  }
}

// ---------------- launch --------------------------------------------------------
extern "C" void kernel_launch(void* const* d_in, const int* in_sizes, int n_in,
                              void* d_out, int out_size, void* d_ws, size_t ws_size,
                              hipStream_t stream) {
  const float* img  = (const float*)d_in[0];
  const float* txt  = (const float*)d_in[1];
  const int*   key  = (const int*)d_in[2];
  const float* logt = (const float*)d_in[3];
  const float* bias = (const float*)d_in[4];

  float* out    = (float*)d_out;
  float* o_loss = out;                                   // [1]
  float* o_sel  = out + 1;                               // [N]
  float* o_zimg = o_sel + N_TXT;                         // [S, 512]
  float* o_ztxt = o_zimg + (size_t)S_IMG * DIM;          // [N, 512]
  float* o_ap   = o_ztxt + (size_t)N_TXT * DIM;          // [S, N]
  float* o_fl   = o_ap + (size_t)S_IMG * N_TXT;          // [N, N]

  char* ws = (char*)d_ws;
  short* zimgb = (short*)ws;                                         // 16 MB
  short* ztxtb = (short*)(ws + (size_t)S_IMG * DIM * 2);             //  4 MB
  short* zselb = (short*)(ws + (size_t)(S_IMG + N_TXT) * DIM * 2);   //  4 MB
  unsigned long long* packed =
      (unsigned long long*)(ws + (size_t)(S_IMG + 2 * N_TXT) * DIM * 2);

  init_kernel<<<N_TXT / 256, 256, 0, stream>>>(packed, o_loss);
  normalize_kernel<<<S_IMG / 4, 256, 0, stream>>>(img, o_zimg, zimgb);
  normalize_kernel<<<N_TXT / 4, 256, 0, stream>>>(txt, o_ztxt, ztxtb);
  tp_select_kernel<<<S_IMG / 4, 256, 0, stream>>>(o_zimg, o_ztxt, key, packed,
                                                  logt, bias);
  gather_kernel<<<N_TXT / 4, 256, 0, stream>>>(packed, o_sel, zimgb, zselb);
  gemm_merged<<<dim3(N_TXT / 128, S_IMG / 128 + N_TXT / 128), 256, 0, stream>>>(
      zimgb, zselb, ztxtb, o_ap, o_fl, logt, bias, o_loss);
}